// Round 3
// baseline (251.206 us; speedup 1.0000x reference)
//
#include <hip/hip_runtime.h>
#include <hip/hip_bf16.h>
#include <stdint.h>

#define B_DIM 8
#define T_DIM 2048
#define H_DIM 512
#define NC 32       // chunks per batch
#define LCH 64      // chunk length (NC*LCH == T_DIM)
#define BM 128
#define BN 128
#define BK 64

typedef float floatx4 __attribute__((ext_vector_type(4)));
typedef __bf16 bf16x8 __attribute__((ext_vector_type(8)));

// ---------------- K1: global min/max of e -> stats[0]=mn, stats[1]=1/(mx-mn)
// Also zeroes the lookback flags for K2 (visible via kernel-boundary release).
__global__ __launch_bounds__(1024) void minmax_kernel(const float* __restrict__ e,
                                                      float* __restrict__ stats,
                                                      int* __restrict__ flags) {
    const float4* e4 = (const float4*)e;
    int tid = threadIdx.x;
    if (tid < B_DIM * NC) flags[tid] = 0;
    float mn = 1e30f, mx = -1e30f;
    #pragma unroll
    for (int i = 0; i < 4; ++i) {
        float4 v = e4[tid + i * 1024];
        mn = fminf(mn, fminf(fminf(v.x, v.y), fminf(v.z, v.w)));
        mx = fmaxf(mx, fmaxf(fmaxf(v.x, v.y), fmaxf(v.z, v.w)));
    }
    for (int off = 32; off > 0; off >>= 1) {
        mn = fminf(mn, __shfl_down(mn, off, 64));
        mx = fmaxf(mx, __shfl_down(mx, off, 64));
    }
    __shared__ float smn[16], smx[16];
    int wid = tid >> 6;
    if ((tid & 63) == 0) { smn[wid] = mn; smx[wid] = mx; }
    __syncthreads();
    if (tid == 0) {
        mn = smn[0]; mx = smx[0];
        #pragma unroll
        for (int w = 1; w < 16; ++w) { mn = fminf(mn, smn[w]); mx = fmaxf(mx, smx[w]); }
        stats[0] = mn;
        stats[1] = 1.0f / (mx - mn);
    }
}

// ---------------- K2: fused scan. Phase 1: local chunk scan + h->bf16 cast,
// publish chunk summary. Phase 2: wait for predecessor chunks' summaries
// (agent-scope acquire), fold carry locally. Phase 3: rescan from h_bf
// (same-block L2-warm) and emit h_agg (bf16).
__global__ __launch_bounds__(512) void fused_scan_kernel(
        const float* __restrict__ e, const float* __restrict__ h,
        const float* __restrict__ stats,
        __hip_bfloat16* __restrict__ h_bf,
        float* __restrict__ Lend, float* __restrict__ PPend, float* __restrict__ LDend,
        __hip_bfloat16* __restrict__ hagg_bf,
        int* __restrict__ flags) {
    const int b = blockIdx.x, c = blockIdx.y, hd = threadIdx.x;
    const int t0 = c * LCH;
    const float mn = stats[0], sc = stats[1];
    const float* eb = e + b * T_DIM;
    const float* hp = h + ((size_t)b * T_DIM + t0) * H_DIM + hd;
    __hip_bfloat16* hbp = h_bf + ((size_t)b * T_DIM + t0) * H_DIM + hd;
    __hip_bfloat16* hop = hagg_bf + ((size_t)b * T_DIM + t0) * H_DIM + hd;

    // Phase 1: local scan with zero-init state
    float lv = 0.0f, ldv = 0.0f, pp = 1.0f;
    #pragma unroll 8
    for (int i = 0; i < LCH; ++i) {
        int t = t0 + i;
        float a = (t == 0) ? 0.0f : (eb[t - 1] - mn) * sc;  // multiplier A_t = x[t-1]
        float hv = hp[(size_t)i * H_DIM];
        lv = fmaf(a, lv, hv);
        ldv = fmaf(a, ldv, 1.0f);
        pp *= a;
        hbp[(size_t)i * H_DIM] = __float2bfloat16(hv);
    }
    Lend[((size_t)b * NC + c) * H_DIM + hd] = lv;
    if (hd == 0) { PPend[b * NC + c] = pp; LDend[b * NC + c] = ldv; }
    __syncthreads();           // drains all threads' vmem (waitcnt vmcnt(0))
    if (hd == 0) {
        __threadfence();       // device-scope release of the summary stores
        __hip_atomic_store(&flags[b * NC + c], 1, __ATOMIC_RELEASE, __HIP_MEMORY_SCOPE_AGENT);
    }

    // Phase 2: wait for predecessors, fold carry locally (no serial chain)
    if (hd < c) {
        while (__hip_atomic_load(&flags[b * NC + hd], __ATOMIC_ACQUIRE,
                                 __HIP_MEMORY_SCOPE_AGENT) == 0) {
            __builtin_amdgcn_s_sleep(2);
        }
    }
    __syncthreads();
    float s = 0.0f, sdv = 0.0f;
    for (int cp = 0; cp < c; ++cp) {
        float pe = PPend[b * NC + cp];
        s   = fmaf(pe, s,   Lend[((size_t)b * NC + cp) * H_DIM + hd]);
        sdv = fmaf(pe, sdv, LDend[b * NC + cp]);
    }

    // Phase 3: rescan from h_bf (L2-warm, written by this block) -> h_agg
    #pragma unroll 8
    for (int i = 0; i < LCH; ++i) {
        int t = t0 + i;
        float a = (t == 0) ? 0.0f : (eb[t - 1] - mn) * sc;
        float hv = __bfloat162float(hbp[(size_t)i * H_DIM]);
        s   = fmaf(a, s, hv);
        sdv = fmaf(a, sdv, 1.0f);
        hop[(size_t)i * H_DIM] = __float2bfloat16(s / sdv);
    }
}

// ---------------- K3: batched NT-GEMM, C[b,t,s] = (1/sqrt(H)) * A[b,t,:] . B[b,s,:]
// BK=64 (half the barriers of BK=32); XOR-swizzled LDS (16B granules) applied on
// the GLOBAL source address, since global_load_lds' LDS dest is fixed base+lane*16.
__device__ __forceinline__ void async16(const void* g, void* l) {
    __builtin_amdgcn_global_load_lds(
        (__attribute__((address_space(1))) void*)g,
        (__attribute__((address_space(3))) void*)l,
        16, 0, 0);
}

__global__ __launch_bounds__(256) void gemm_kernel(
        const __hip_bfloat16* __restrict__ Abf,   // h_bf   [B][T][H]
        const __hip_bfloat16* __restrict__ Bbf,   // hagg_bf[B][T][H]
        float* __restrict__ C) {                  // [B][T][T]
    __shared__ __align__(16) __hip_bfloat16 As[BM * BK];   // 16 KB
    __shared__ __align__(16) __hip_bfloat16 Bs[BN * BK];   // 16 KB
    const int b = blockIdx.z;
    const int tm = blockIdx.x * BM;
    const int sn = blockIdx.y * BN;
    const int tid = threadIdx.x;
    const int lane = tid & 63;
    const int wave = tid >> 6;
    const int wm = (wave >> 1) * 64;
    const int wn = (wave & 1) * 64;
    const int l16 = lane & 15;
    const int quad = lane >> 4;

    // Staging: thread tid fills LDS granule (row=tid>>3, slot=tid&7) of each
    // 32-row chunk; slot g holds global k-granule g ^ (row&7).
    const int srow = tid >> 3;
    const int sgran = (tid & 7) ^ (srow & 7);
    const __hip_bfloat16* Ag = Abf + ((size_t)b * T_DIM + tm + srow) * H_DIM + sgran * 8;
    const __hip_bfloat16* Bg = Bbf + ((size_t)b * T_DIM + sn + srow) * H_DIM + sgran * 8;
    char* AsB = (char*)As;
    char* BsB = (char*)Bs;

    floatx4 zero = {0.0f, 0.0f, 0.0f, 0.0f};
    floatx4 acc[4][4];
    #pragma unroll
    for (int i = 0; i < 4; ++i)
        #pragma unroll
        for (int j = 0; j < 4; ++j) acc[i][j] = zero;

    for (int kk = 0; kk < H_DIM; kk += BK) {
        __syncthreads();   // protect previous iteration's LDS reads
        #pragma unroll
        for (int q = 0; q < 4; ++q) {
            async16(Ag + (size_t)q * 32 * H_DIM + kk, AsB + q * 4096 + tid * 16);
            async16(Bg + (size_t)q * 32 * H_DIM + kk, BsB + q * 4096 + tid * 16);
        }
        asm volatile("s_waitcnt vmcnt(0)" ::: "memory");
        __syncthreads();

        bf16x8 af[2][4], bfv[2][4];
        #pragma unroll
        for (int ku = 0; ku < 2; ++ku)
            #pragma unroll
            for (int i = 0; i < 4; ++i) {
                int ra = wm + i * 16 + l16;
                int rb = wn + i * 16 + l16;
                int ga = (ku * 4 + quad) ^ (l16 & 7);
                af[ku][i]  = *reinterpret_cast<const bf16x8*>(AsB + ra * 128 + ga * 16);
                bfv[ku][i] = *reinterpret_cast<const bf16x8*>(BsB + rb * 128 + ga * 16);
            }
        #pragma unroll
        for (int ku = 0; ku < 2; ++ku)
            #pragma unroll
            for (int i = 0; i < 4; ++i)
                #pragma unroll
                for (int j = 0; j < 4; ++j)
                    acc[i][j] = __builtin_amdgcn_mfma_f32_16x16x32_bf16(af[ku][i], bfv[ku][j], acc[i][j], 0, 0, 0);
    }

    const float scale = 0.04419417382415922f;  // 1/sqrt(512)
    float* Cp = C + (size_t)b * T_DIM * T_DIM;
    #pragma unroll
    for (int i = 0; i < 4; ++i) {
        int row0 = tm + wm + i * 16 + quad * 4;
        #pragma unroll
        for (int j = 0; j < 4; ++j) {
            int col = sn + wn + j * 16 + l16;
            #pragma unroll
            for (int r = 0; r < 4; ++r)
                Cp[(size_t)(row0 + r) * T_DIM + col] = acc[i][j][r] * scale;
        }
    }
}

extern "C" void kernel_launch(void* const* d_in, const int* in_sizes, int n_in,
                              void* d_out, int out_size, void* d_ws, size_t ws_size,
                              hipStream_t stream) {
    const float* e = (const float*)d_in[0];
    const float* h = (const float*)d_in[1];
    // d_in[2] (ilens) is unused by the reference output.
    float* out = (float*)d_out;

    char* ws = (char*)d_ws;
    float* stats            = (float*)ws;                                    // 256 B
    int* flags              = (int*)(ws + 256);                              // 1 KB + pad
    __hip_bfloat16* h_bf    = (__hip_bfloat16*)(ws + 4096);                  // 16 MB
    __hip_bfloat16* hagg_bf = (__hip_bfloat16*)(ws + 4096 + (16u << 20));    // 16 MB
    char* p = ws + 4096 + (32u << 20);
    float* Lend  = (float*)p;   p += (size_t)B_DIM * NC * H_DIM * 4;         // 512 KB
    float* PPend = (float*)p;   p += B_DIM * NC * 4;                         // 1 KB
    float* LDend = (float*)p;

    minmax_kernel<<<1, 1024, 0, stream>>>(e, stats, flags);
    fused_scan_kernel<<<dim3(B_DIM, NC), 512, 0, stream>>>(
        e, h, stats, h_bf, Lend, PPend, LDend, hagg_bf, flags);
    gemm_kernel<<<dim3(T_DIM / BM, T_DIM / BN, B_DIM), 256, 0, stream>>>(h_bf, hagg_bf, out);
}

// Round 4
// 234.082 us; speedup vs baseline: 1.0732x; 1.0732x over previous
//
#include <hip/hip_runtime.h>
#include <hip/hip_bf16.h>
#include <stdint.h>

#define B_DIM 8
#define T_DIM 2048
#define H_DIM 512
#define NC 32       // chunks per batch
#define LCH 64      // chunk length
#define NSUB 4      // sub-chunks per chunk
#define LSUB 16     // steps per sub-chunk
#define NSEG (NC * NSUB)   // 128 segments per batch
#define BM 128
#define BN 128
#define BK 64

typedef float floatx4 __attribute__((ext_vector_type(4)));
typedef __bf16 bf16x4 __attribute__((ext_vector_type(4)));
typedef __bf16 bf16x8 __attribute__((ext_vector_type(8)));

// ---------------- K1: global min/max of e -> stats[0]=mn, stats[1]=1/(mx-mn)
__global__ __launch_bounds__(1024) void minmax_kernel(const float* __restrict__ e,
                                                      float* __restrict__ stats) {
    const float4* e4 = (const float4*)e;
    int tid = threadIdx.x;
    float mn = 1e30f, mx = -1e30f;
    #pragma unroll
    for (int i = 0; i < 4; ++i) {
        float4 v = e4[tid + i * 1024];
        mn = fminf(mn, fminf(fminf(v.x, v.y), fminf(v.z, v.w)));
        mx = fmaxf(mx, fmaxf(fmaxf(v.x, v.y), fmaxf(v.z, v.w)));
    }
    for (int off = 32; off > 0; off >>= 1) {
        mn = fminf(mn, __shfl_down(mn, off, 64));
        mx = fmaxf(mx, __shfl_down(mx, off, 64));
    }
    __shared__ float smn[16], smx[16];
    int wid = tid >> 6;
    if ((tid & 63) == 0) { smn[wid] = mn; smx[wid] = mx; }
    __syncthreads();
    if (tid == 0) {
        mn = smn[0]; mx = smx[0];
        #pragma unroll
        for (int w = 1; w < 16; ++w) { mn = fminf(mn, smn[w]); mx = fmaxf(mx, smx[w]); }
        stats[0] = mn;
        stats[1] = 1.0f / (mx - mn);
    }
}

// ---------------- K2: per-sub-chunk local scan (zero-init), emit h_bf + per-sub summaries.
// Thread layout: hdq = tid&127 (4 h-dims via float4), sub = tid>>7 (16 t-steps).
__global__ __launch_bounds__(512) void chunk_sum_kernel(
        const float* __restrict__ e, const float* __restrict__ h,
        const float* __restrict__ stats,
        __hip_bfloat16* __restrict__ h_bf,
        float* __restrict__ Lsub, float* __restrict__ PPsub, float* __restrict__ LDsub) {
    const int b = blockIdx.x, c = blockIdx.y;
    const int tid = threadIdx.x;
    const int hdq = tid & 127, sub = tid >> 7;
    const int hd = hdq * 4;
    const int t0 = c * LCH + sub * LSUB;

    __shared__ float se[LCH];   // multiplier a for step j of this chunk
    if (tid < LCH) {
        int t = c * LCH + tid;
        se[tid] = (t == 0) ? 0.0f : (e[b * T_DIM + t - 1] - stats[0]) * stats[1];
    }
    __syncthreads();

    const float* hp = h + ((size_t)b * T_DIM + t0) * H_DIM + hd;
    __hip_bfloat16* hbp = h_bf + ((size_t)b * T_DIM + t0) * H_DIM + hd;

    floatx4 lv = {0.0f, 0.0f, 0.0f, 0.0f};
    float ldv = 0.0f, pp = 1.0f;
    #pragma unroll 8
    for (int i = 0; i < LSUB; ++i) {
        float a = se[sub * LSUB + i];
        floatx4 hv = *(const floatx4*)(hp + (size_t)i * H_DIM);
        lv = a * lv + hv;
        ldv = fmaf(a, ldv, 1.0f);
        pp *= a;
        bf16x4 o;
        #pragma unroll
        for (int k = 0; k < 4; ++k) o[k] = (__bf16)hv[k];
        *(bf16x4*)(hbp + (size_t)i * H_DIM) = o;
    }
    int seg = (b * NC + c) * NSUB + sub;
    *(floatx4*)(Lsub + (size_t)seg * H_DIM + hd) = lv;
    if (hdq == 0) { PPsub[seg] = pp; LDsub[seg] = ldv; }
}

// ---------------- K3: serial fold over 128 segments per batch -> entering states.
__global__ __launch_bounds__(512) void carry_kernel(
        const float* __restrict__ Lsub, const float* __restrict__ PPsub,
        const float* __restrict__ LDsub,
        float* __restrict__ Ssub, float* __restrict__ SDsub) {
    const int b = blockIdx.x, hd = threadIdx.x;
    float s = 0.0f, sd = 0.0f;
    #pragma unroll 4
    for (int g = 0; g < NSEG; ++g) {
        int seg = b * NSEG + g;
        Ssub[(size_t)seg * H_DIM + hd] = s;
        if (hd == 0) SDsub[seg] = sd;
        float pe = PPsub[seg];
        s  = fmaf(pe, s,  Lsub[(size_t)seg * H_DIM + hd]);
        sd = fmaf(pe, sd, LDsub[seg]);
    }
}

// ---------------- K4: rescan sub-chunk from h_bf with carried-in state -> h_agg (bf16).
__global__ __launch_bounds__(512) void rescan_kernel(
        const float* __restrict__ e, const __hip_bfloat16* __restrict__ h_bf,
        const float* __restrict__ stats,
        const float* __restrict__ Ssub, const float* __restrict__ SDsub,
        __hip_bfloat16* __restrict__ hagg_bf) {
    const int b = blockIdx.x, c = blockIdx.y;
    const int tid = threadIdx.x;
    const int hdq = tid & 127, sub = tid >> 7;
    const int hd = hdq * 4;
    const int t0 = c * LCH + sub * LSUB;

    __shared__ float se[LCH];
    if (tid < LCH) {
        int t = c * LCH + tid;
        se[tid] = (t == 0) ? 0.0f : (e[b * T_DIM + t - 1] - stats[0]) * stats[1];
    }
    __syncthreads();

    const int seg = (b * NC + c) * NSUB + sub;
    const __hip_bfloat16* hbp = h_bf + ((size_t)b * T_DIM + t0) * H_DIM + hd;
    __hip_bfloat16* hop = hagg_bf + ((size_t)b * T_DIM + t0) * H_DIM + hd;

    floatx4 s = *(const floatx4*)(Ssub + (size_t)seg * H_DIM + hd);
    float sd = SDsub[seg];
    #pragma unroll 8
    for (int i = 0; i < LSUB; ++i) {
        float a = se[sub * LSUB + i];
        bf16x4 hb = *(const bf16x4*)(hbp + (size_t)i * H_DIM);
        floatx4 hv;
        #pragma unroll
        for (int k = 0; k < 4; ++k) hv[k] = (float)hb[k];
        s = a * s + hv;
        sd = fmaf(a, sd, 1.0f);
        float inv = 1.0f / sd;
        bf16x4 o;
        #pragma unroll
        for (int k = 0; k < 4; ++k) o[k] = (__bf16)(s[k] * inv);
        *(bf16x4*)(hop + (size_t)i * H_DIM) = o;
    }
}

// ---------------- K5: batched NT-GEMM, C[b,t,s] = (1/sqrt(H)) * A[b,t,:] . B[b,s,:]
__device__ __forceinline__ void async16(const void* g, void* l) {
    __builtin_amdgcn_global_load_lds(
        (__attribute__((address_space(1))) void*)g,
        (__attribute__((address_space(3))) void*)l,
        16, 0, 0);
}

__global__ __launch_bounds__(256) void gemm_kernel(
        const __hip_bfloat16* __restrict__ Abf,   // h_bf   [B][T][H]
        const __hip_bfloat16* __restrict__ Bbf,   // hagg_bf[B][T][H]
        float* __restrict__ C) {                  // [B][T][T]
    __shared__ __align__(16) __hip_bfloat16 As[BM * BK];   // 16 KB
    __shared__ __align__(16) __hip_bfloat16 Bs[BN * BK];   // 16 KB
    const int b = blockIdx.z;
    const int tm = blockIdx.x * BM;
    const int sn = blockIdx.y * BN;
    const int tid = threadIdx.x;
    const int lane = tid & 63;
    const int wave = tid >> 6;
    const int wm = (wave >> 1) * 64;
    const int wn = (wave & 1) * 64;
    const int l16 = lane & 15;
    const int quad = lane >> 4;

    // Staging: thread tid fills LDS granule (row=tid>>3, slot=tid&7) of each
    // 32-row chunk; slot g holds global k-granule g ^ (row&7)  (XOR swizzle on
    // the GLOBAL side — global_load_lds' LDS dest is fixed base+lane*16).
    const int srow = tid >> 3;
    const int sgran = (tid & 7) ^ (srow & 7);
    const __hip_bfloat16* Ag = Abf + ((size_t)b * T_DIM + tm + srow) * H_DIM + sgran * 8;
    const __hip_bfloat16* Bg = Bbf + ((size_t)b * T_DIM + sn + srow) * H_DIM + sgran * 8;
    char* AsB = (char*)As;
    char* BsB = (char*)Bs;

    floatx4 zero = {0.0f, 0.0f, 0.0f, 0.0f};
    floatx4 acc[4][4];
    #pragma unroll
    for (int i = 0; i < 4; ++i)
        #pragma unroll
        for (int j = 0; j < 4; ++j) acc[i][j] = zero;

    for (int kk = 0; kk < H_DIM; kk += BK) {
        __syncthreads();   // protect previous iteration's LDS reads
        #pragma unroll
        for (int q = 0; q < 4; ++q) {
            async16(Ag + (size_t)q * 32 * H_DIM + kk, AsB + q * 4096 + tid * 16);
            async16(Bg + (size_t)q * 32 * H_DIM + kk, BsB + q * 4096 + tid * 16);
        }
        asm volatile("s_waitcnt vmcnt(0)" ::: "memory");
        __syncthreads();

        bf16x8 af[2][4], bfv[2][4];
        #pragma unroll
        for (int ku = 0; ku < 2; ++ku)
            #pragma unroll
            for (int i = 0; i < 4; ++i) {
                int ra = wm + i * 16 + l16;
                int rb = wn + i * 16 + l16;
                int ga = (ku * 4 + quad) ^ (l16 & 7);
                af[ku][i]  = *reinterpret_cast<const bf16x8*>(AsB + ra * 128 + ga * 16);
                bfv[ku][i] = *reinterpret_cast<const bf16x8*>(BsB + rb * 128 + ga * 16);
            }
        #pragma unroll
        for (int ku = 0; ku < 2; ++ku)
            #pragma unroll
            for (int i = 0; i < 4; ++i)
                #pragma unroll
                for (int j = 0; j < 4; ++j)
                    acc[i][j] = __builtin_amdgcn_mfma_f32_16x16x32_bf16(af[ku][i], bfv[ku][j], acc[i][j], 0, 0, 0);
    }

    const float scale = 0.04419417382415922f;  // 1/sqrt(512)
    float* Cp = C + (size_t)b * T_DIM * T_DIM;
    #pragma unroll
    for (int i = 0; i < 4; ++i) {
        int row0 = tm + wm + i * 16 + quad * 4;
        #pragma unroll
        for (int j = 0; j < 4; ++j) {
            int col = sn + wn + j * 16 + l16;
            #pragma unroll
            for (int r = 0; r < 4; ++r)
                Cp[(size_t)(row0 + r) * T_DIM + col] = acc[i][j][r] * scale;
        }
    }
}

extern "C" void kernel_launch(void* const* d_in, const int* in_sizes, int n_in,
                              void* d_out, int out_size, void* d_ws, size_t ws_size,
                              hipStream_t stream) {
    const float* e = (const float*)d_in[0];
    const float* h = (const float*)d_in[1];
    // d_in[2] (ilens) is unused by the reference output.
    float* out = (float*)d_out;

    char* ws = (char*)d_ws;
    float* stats            = (float*)ws;                                    // 256 B
    __hip_bfloat16* h_bf    = (__hip_bfloat16*)(ws + 4096);                  // 16 MB
    __hip_bfloat16* hagg_bf = (__hip_bfloat16*)(ws + 4096 + (16u << 20));    // 16 MB
    char* p = ws + 4096 + (32u << 20);
    float* Lsub  = (float*)p;   p += (size_t)B_DIM * NSEG * H_DIM * 4;       // 2 MB
    float* Ssub  = (float*)p;   p += (size_t)B_DIM * NSEG * H_DIM * 4;       // 2 MB
    float* PPsub = (float*)p;   p += B_DIM * NSEG * 4;                       // 4 KB
    float* LDsub = (float*)p;   p += B_DIM * NSEG * 4;                       // 4 KB
    float* SDsub = (float*)p;

    minmax_kernel<<<1, 1024, 0, stream>>>(e, stats);
    chunk_sum_kernel<<<dim3(B_DIM, NC), 512, 0, stream>>>(e, h, stats, h_bf, Lsub, PPsub, LDsub);
    carry_kernel<<<B_DIM, 512, 0, stream>>>(Lsub, PPsub, LDsub, Ssub, SDsub);
    rescan_kernel<<<dim3(B_DIM, NC), 512, 0, stream>>>(e, h_bf, stats, Ssub, SDsub, hagg_bf);
    gemm_kernel<<<dim3(T_DIM / BM, T_DIM / BN, B_DIM), 256, 0, stream>>>(h_bf, hagg_bf, out);
}